// Round 1
// baseline (967.515 us; speedup 1.0000x reference)
//
#include <hip/hip_runtime.h>
#include <hip/hip_bf16.h>

#define BH 128
#define SEQ 1024
#define DH 64
#define MT 16          // query rows per block
#define NW 256         // keys per wave
#define PSTRIDE 1032   // P_lds row stride in shorts (padded +8 to break bank conflicts)

typedef __attribute__((ext_vector_type(8))) short short8;
typedef __attribute__((ext_vector_type(4))) float float4v;

__device__ __forceinline__ short bf16_rne(float x) {
    unsigned u = __builtin_bit_cast(unsigned, x);
    unsigned r = (u + 0x7fffu + ((u >> 16) & 1u)) >> 16;
    return (short)r;
}

// hi = truncated bf16, lo = RNE bf16 of the residual (x ~= hi + lo to ~2^-17 rel)
__device__ __forceinline__ void bf16_split(float x, short& hi, short& lo) {
    unsigned u = __builtin_bit_cast(unsigned, x);
    hi = (short)(u >> 16);
    float hf = __builtin_bit_cast(float, u & 0xffff0000u);
    float res = x - hf;
    unsigned v = __builtin_bit_cast(unsigned, res);
    lo = (short)((v + 0x7fffu + ((v >> 16) & 1u)) >> 16);
}

__global__ __launch_bounds__(256, 2)
void Attention_66889820668421_kernel(const float* __restrict__ Q,
                                     const float* __restrict__ K,
                                     const float* __restrict__ V,
                                     const int*   __restrict__ mask,
                                     float* __restrict__ out,
                                     float* __restrict__ pattn)
{
    __shared__ short P_lds[MT * PSTRIDE];          // 33 KB: p tile, bf16
    __shared__ float out_red[4][MT][DH];           // 16 KB: per-wave partial PV
    __shared__ float red_max[4][MT];
    __shared__ float red_sum[4][MT];

    const int tid  = threadIdx.x;
    const int wave = tid >> 6;
    const int lane = tid & 63;
    const int q    = lane >> 4;     // quad 0..3
    const int l    = lane & 15;
    const int bh   = blockIdx.y;
    const int m0   = blockIdx.x * MT;
    const int nbase = wave * NW;

    // ---------------- Q fragments (split hi/lo), 2 K-steps of 32 ----------------
    short8 a_hi[2], a_lo[2];
    {
        const float* qrow = Q + (size_t)(bh * SEQ + m0 + l) * DH;
        #pragma unroll
        for (int s = 0; s < 2; ++s) {
            float4v x0 = *(const float4v*)(qrow + s * 32 + q * 8);
            float4v x1 = *(const float4v*)(qrow + s * 32 + q * 8 + 4);
            #pragma unroll
            for (int j = 0; j < 4; ++j) {
                short h, lo2;
                bf16_split(x0[j], h, lo2); a_hi[s][j] = h; a_lo[s][j] = lo2;
                bf16_split(x1[j], h, lo2); a_hi[s][4 + j] = h; a_lo[s][4 + j] = lo2;
            }
        }
    }

    // ---------------- QK^T: 16 tiles of 16 keys, split-precision MFMA ------------
    float4v acc[16];
    int mv[16];
    #pragma unroll
    for (int t = 0; t < 16; ++t) {
        const int key = nbase + t * 16 + l;
        const float* krow = K + (size_t)(bh * SEQ + key) * DH;
        float4v a = {0.f, 0.f, 0.f, 0.f};
        #pragma unroll
        for (int s = 0; s < 2; ++s) {
            float4v x0 = *(const float4v*)(krow + s * 32 + q * 8);
            float4v x1 = *(const float4v*)(krow + s * 32 + q * 8 + 4);
            short8 bhh, bll;
            #pragma unroll
            for (int j = 0; j < 4; ++j) {
                short h, lo2;
                bf16_split(x0[j], h, lo2); bhh[j] = h; bll[j] = lo2;
                bf16_split(x1[j], h, lo2); bhh[4 + j] = h; bll[4 + j] = lo2;
            }
            a = __builtin_amdgcn_mfma_f32_16x16x32_bf16(a_hi[s], bhh, a, 0, 0, 0);
            a = __builtin_amdgcn_mfma_f32_16x16x32_bf16(a_hi[s], bll, a, 0, 0, 0);
            a = __builtin_amdgcn_mfma_f32_16x16x32_bf16(a_lo[s], bhh, a, 0, 0, 0);
        }
        mv[t] = mask[bh * SEQ + nbase + t * 16 + l];
        acc[t] = a;
    }

    // ---------------- scale + mask + row max ----------------
    const float scale = 0.03125f;   // 1/sqrt(1024)
    float pm[4] = {-3e38f, -3e38f, -3e38f, -3e38f};
    #pragma unroll
    for (int t = 0; t < 16; ++t) {
        const bool ok = (mv[t] != 0);
        #pragma unroll
        for (int r = 0; r < 4; ++r) {
            float s = ok ? acc[t][r] * scale : -1e9f;
            acc[t][r] = s;
            pm[r] = fmaxf(pm[r], s);
        }
    }
    #pragma unroll
    for (int off = 1; off < 16; off <<= 1) {
        #pragma unroll
        for (int r = 0; r < 4; ++r)
            pm[r] = fmaxf(pm[r], __shfl_xor(pm[r], off));
    }
    if (l == 0) {
        #pragma unroll
        for (int r = 0; r < 4; ++r) red_max[wave][q * 4 + r] = pm[r];
    }
    __syncthreads();

    float rm[4];
    #pragma unroll
    for (int r = 0; r < 4; ++r) {
        const int row = q * 4 + r;
        rm[r] = fmaxf(fmaxf(red_max[0][row], red_max[1][row]),
                      fmaxf(red_max[2][row], red_max[3][row]));
    }

    // ---------------- exp + row sum ----------------
    float ps[4] = {0.f, 0.f, 0.f, 0.f};
    #pragma unroll
    for (int t = 0; t < 16; ++t) {
        #pragma unroll
        for (int r = 0; r < 4; ++r) {
            float e = __expf(acc[t][r] - rm[r]);
            acc[t][r] = e;
            ps[r] += e;
        }
    }
    #pragma unroll
    for (int off = 1; off < 16; off <<= 1) {
        #pragma unroll
        for (int r = 0; r < 4; ++r)
            ps[r] += __shfl_xor(ps[r], off);
    }
    if (l == 0) {
        #pragma unroll
        for (int r = 0; r < 4; ++r) red_sum[wave][q * 4 + r] = ps[r];
    }
    __syncthreads();

    float inv[4];
    #pragma unroll
    for (int r = 0; r < 4; ++r) {
        const int row = q * 4 + r;
        inv[r] = 1.0f / (red_sum[0][row] + red_sum[1][row] +
                         red_sum[2][row] + red_sum[3][row]);
    }

    // ---------------- normalize, write p (fp32 global) + P_lds (bf16) -----------
    float* prow = pattn + ((size_t)bh * SEQ + m0) * SEQ;
    #pragma unroll
    for (int t = 0; t < 16; ++t) {
        const int col = nbase + t * 16 + l;
        #pragma unroll
        for (int r = 0; r < 4; ++r) {
            const int row = q * 4 + r;
            float p = acc[t][r] * inv[r];
            prow[(size_t)row * SEQ + col] = p;
            P_lds[row * PSTRIDE + col] = bf16_rne(p);
        }
    }
    __syncthreads();

    // ---------------- PV: each wave multiplies its 256-key chunk -----------------
    float4v ao[4];
    #pragma unroll
    for (int dt = 0; dt < 4; ++dt) ao[dt] = (float4v){0.f, 0.f, 0.f, 0.f};

    #pragma unroll 2
    for (int step = 0; step < 8; ++step) {
        const int key0 = nbase + step * 32;
        short8 pa = *(const short8*)&P_lds[l * PSTRIDE + key0 + q * 8];
        const float* vbase = V + (size_t)(bh * SEQ + key0 + q * 8) * DH + l;
        #pragma unroll
        for (int dt = 0; dt < 4; ++dt) {
            short8 vb;
            #pragma unroll
            for (int j = 0; j < 8; ++j)
                vb[j] = bf16_rne(vbase[(size_t)j * DH + dt * 16]);
            ao[dt] = __builtin_amdgcn_mfma_f32_16x16x32_bf16(pa, vb, ao[dt], 0, 0, 0);
        }
    }

    // ---------------- cross-wave reduce + store out ------------------------------
    #pragma unroll
    for (int dt = 0; dt < 4; ++dt) {
        #pragma unroll
        for (int r = 0; r < 4; ++r)
            out_red[wave][q * 4 + r][dt * 16 + l] = ao[dt][r];
    }
    __syncthreads();

    #pragma unroll
    for (int i = 0; i < 4; ++i) {
        const int e = tid + 256 * i;
        const int row = e >> 6;
        const int d = e & 63;
        float s = out_red[0][row][d] + out_red[1][row][d] +
                  out_red[2][row][d] + out_red[3][row][d];
        out[(size_t)(bh * SEQ + m0 + row) * DH + d] = s;
    }
}

extern "C" void kernel_launch(void* const* d_in, const int* in_sizes, int n_in,
                              void* d_out, int out_size, void* d_ws, size_t ws_size,
                              hipStream_t stream) {
    const float* Q    = (const float*)d_in[0];
    const float* K    = (const float*)d_in[1];
    const float* V    = (const float*)d_in[2];
    const int*   mask = (const int*)d_in[3];
    float* out   = (float*)d_out;
    float* pattn = out + (size_t)BH * SEQ * DH;   // outputs concatenated: out, p_attn

    dim3 grid(SEQ / MT, BH);   // 64 x 128 = 8192 blocks
    Attention_66889820668421_kernel<<<grid, 256, 0, stream>>>(Q, K, V, mask, out, pattn);
}